// Round 4
// baseline (280.380 us; speedup 1.0000x reference)
//
#include <hip/hip_runtime.h>
#include <math.h>

// CoPE2d: B=8, HEADS=12, H=W=24, SEQ=576, D=64, NPOS=24
#define NH 12
#define S 576
#define DD 64
#define P 24
#define NROWS 55296                 // rows per unit (x or y)
#define PSTRIDE 32                  // padded bf16 row stride (64 B) for MFMA K=32

typedef unsigned int uint;
typedef unsigned short ushort;
typedef __bf16 bf16x8 __attribute__((ext_vector_type(8)));
typedef float f32x4 __attribute__((ext_vector_type(4)));

__device__ __forceinline__ uint bf16hi_bits(float v) {
    const uint u = __float_as_uint(v);
    return u + 0x7FFFu + ((u >> 16) & 1u);   // rne; use >>16 or &0xFFFF0000
}

// ---------------------------------------------------------------------------
// K1 (fused gather+cope): one block stages 16 attn rows (coalesced float4
// stream over the full 127 MB, read exactly once). attn row r=a*24+b of
// matrix (bb,hd) feeds BOTH the x-row (t2=bb*288+hd*24+a, l=b; contiguous
// cols) and the y-row (t2=bb*288+hd*24+b, l=a; stride-24 cols). 32 groups
// of 8 threads: groups 0-15 -> x-rows, 16-31 -> y-rows. Output: bf16 hi/lo
// rows (g-major, PSTRIDE pad, zeroed) + fp32 sq norms.
// ---------------------------------------------------------------------------
__global__ __launch_bounds__(256) void cope2_kernel(
    const float* __restrict__ attn, const float* __restrict__ q,
    const float* __restrict__ Ex, const float* __restrict__ Ey,
    __bf16* __restrict__ pxh, __bf16* __restrict__ pxl,
    __bf16* __restrict__ pyh, __bf16* __restrict__ pyl,
    float* __restrict__ sqx, float* __restrict__ sqy)
{
    __shared__ float rb[16][580];      // staged attn rows (pad 580 vs banks)
    __shared__ float Et[2][24][68];    // E transposed: Et[u][p][d]
    __shared__ float Lr[32][28];       // logits per unit-row
    __shared__ float Wr[32][28];       // interp outputs per unit-row

    const int tid = threadIdx.x;
    const int r0 = blockIdx.x * 16;
    const int hd = blockIdx.y, bb = blockIdx.z;

    // stage 16 attn rows: 2304 float4, fully coalesced
    const float4* src = (const float4*)(attn + ((long)(bb * NH + hd) * S + r0) * S);
    #pragma unroll
    for (int it = 0; it < 9; ++it) {
        const int i = it * 256 + tid;
        *(float4*)&rb[i / 144][(i % 144) * 4] = src[i];
    }
    // stage both E matrices transposed
    for (int i = tid; i < 1536; i += 256) {
        const int d = i / 24, p = i % 24;
        Et[0][p][d] = Ex[i];
        Et[1][p][d] = Ey[i];
    }
    __syncthreads();

    // ---- group decode ----
    const int grp = tid >> 3, j = tid & 7;
    const int is_y = grp >> 4;
    const int rowloc = grp & 15;
    const int r = r0 + rowloc;
    const int a = r / 24, b = r % 24;
    const int t2 = bb * 288 + hd * 24 + (is_y ? b : a);
    const int l  = is_y ? a : b;
    const int h  = t2 % 12, n = t2 / 12;       // PROPER decode for q / output
    const int bq = n / 24, oq = n % 24;
    const int qr = is_y ? (l * 24 + oq) : (oq * 24 + l);
    const int gm = bq * NH + h;

    // ---- phase 1: logits p in {j, j+8, j+16} (q via broadcast-coalesced
    // global float4; Et via broadcast LDS) ----
    const float* qrow = q + ((long)gm * S + qr) * DD;
    float a0 = 0.f, a1 = 0.f, a2 = 0.f;
    #pragma unroll
    for (int d4 = 0; d4 < DD; d4 += 4) {
        const float4 qv = *(const float4*)(qrow + d4);
        const float4 e0 = *(const float4*)&Et[is_y][j][d4];
        const float4 e1 = *(const float4*)&Et[is_y][j + 8][d4];
        const float4 e2 = *(const float4*)&Et[is_y][j + 16][d4];
        a0 = fmaf(qv.x, e0.x, fmaf(qv.y, e0.y, fmaf(qv.z, e0.z, fmaf(qv.w, e0.w, a0))));
        a1 = fmaf(qv.x, e1.x, fmaf(qv.y, e1.y, fmaf(qv.z, e1.z, fmaf(qv.w, e1.w, a1))));
        a2 = fmaf(qv.x, e2.x, fmaf(qv.y, e2.y, fmaf(qv.z, e2.z, fmaf(qv.w, e2.w, a2))));
    }
    Lr[grp][j] = a0; Lr[grp][j + 8] = a1; Lr[grp][j + 16] = a2;

    // ---- phase 2: gates from staged row -> sigmoid -> suffix scan -> interp ----
    float g0, g1, g2;
    if (is_y) {
        g0 = rb[rowloc][(3 * j + 0) * 24 + b];
        g1 = rb[rowloc][(3 * j + 1) * 24 + b];
        g2 = rb[rowloc][(3 * j + 2) * 24 + b];
    } else {
        g0 = rb[rowloc][a * 24 + 3 * j + 0];
        g1 = rb[rowloc][a * 24 + 3 * j + 1];
        g2 = rb[rowloc][a * 24 + 3 * j + 2];
    }
    g0 = 1.0f / (1.0f + __expf(-g0));
    g1 = 1.0f / (1.0f + __expf(-g1));
    g2 = 1.0f / (1.0f + __expf(-g2));
    const float s = g0 + g1 + g2;
    float T = s;                                 // inclusive suffix sum over 8 lanes
    #pragma unroll
    for (int d = 1; d < 8; d <<= 1) {
        const float o = __shfl_down(T, d, 8);
        T += (j + d < 8) ? o : 0.0f;
    }
    const float Exc = T - s;
    float posv[3];
    posv[0] = T;
    posv[1] = g1 + g2 + Exc;
    posv[2] = g2 + Exc;

    float sqp = 0.f;
    #pragma unroll
    for (int m = 0; m < 3; ++m) {
        const float pk  = fminf(posv[m], 23.0f);
        const float pf  = floorf(pk);
        const int   ic  = (int)ceilf(pk);
        const int   ifl = (int)pf;
        const float w   = pk - pf;
        const float o   = Lr[grp][ic] * w + Lr[grp][ifl] * (1.0f - w);
        Wr[grp][3 * j + m] = o;
        sqp += o * o;
    }
    #pragma unroll
    for (int d = 1; d < 8; d <<= 1) {
        const float o = __shfl_down(sqp, d, 8);
        sqp += (j + d < 8) ? o : 0.0f;
    }
    if (j == 0) (is_y ? sqy : sqx)[(long)gm * S + qr] = sqp;
    __syncthreads();

    // ---- phase 3: pack hi/lo bf16, 16 B/thread, zero the K-pad ----
    const int hl = tid >> 7, rem = tid & 127;
    const int grp3 = rem >> 2, seg = rem & 3;
    const int is_y3 = grp3 >> 4;
    const int r3 = r0 + (grp3 & 15);
    const int a3 = r3 / 24, b3 = r3 % 24;
    const int t23 = bb * 288 + hd * 24 + (is_y3 ? b3 : a3);
    const int l3  = is_y3 ? a3 : b3;
    const int h3  = t23 % 12, n3 = t23 / 12;
    const int bq3 = n3 / 24, oq3 = n3 % 24;
    const int qr3 = is_y3 ? (l3 * 24 + oq3) : (oq3 * 24 + l3);
    const int gm3 = bq3 * NH + h3;
    __bf16* dst = (is_y3 ? (hl ? pyl : pyh) : (hl ? pxl : pxh))
                  + ((long)gm3 * S + qr3) * PSTRIDE + seg * 8;
    uint pk4[4] = {0u, 0u, 0u, 0u};
    if (seg < 3) {
        ushort hv[8];
        #pragma unroll
        for (int t = 0; t < 8; ++t) {
            const float o = Wr[grp3][seg * 8 + t];
            const uint rh = bf16hi_bits(o);
            if (hl == 0) {
                hv[t] = (ushort)(rh >> 16);
            } else {
                const float hif = __uint_as_float(rh & 0xFFFF0000u);
                hv[t] = (ushort)(bf16hi_bits(o - hif) >> 16);
            }
        }
        #pragma unroll
        for (int t = 0; t < 4; ++t)
            pk4[t] = (uint)hv[2 * t] | ((uint)hv[2 * t + 1] << 16);
    }
    *(uint4*)dst = make_uint4(pk4[0], pk4[1], pk4[2], pk4[3]);
}

// ---------------------------------------------------------------------------
// K2: MFMA Gram + cdist + blend. Flat grid: 7776 tiles = 1944 blocks x 4
// waves, no waste. Padded 64-B rows -> every frag load is a coalesced 1-KB
// wave load; add-only addressing.
// ---------------------------------------------------------------------------
__global__ __launch_bounds__(256) void dist_kernel(
    const __bf16* __restrict__ pxh, const __bf16* __restrict__ pxl,
    const __bf16* __restrict__ pyh, const __bf16* __restrict__ pyl,
    const float* __restrict__ sqx, const float* __restrict__ sqy,
    const float* __restrict__ wxp, float* __restrict__ out)
{
    const int tid = threadIdx.x;
    const int lane = tid & 63;
    const int tg = blockIdx.x * 4 + (tid >> 6);   // global tile id, < 7776
    const int g = tg / 81;
    const int til = tg - g * 81;
    const int tn = til / 9, tm = til - tn * 9;
    const int lm = lane & 15, kg = lane >> 4;
    const float wx = wxp[0], wyc = 1.0f - wx;
    const long gb = (long)g * S;

    // persistent B frags (m-side)
    bf16x8 xbh[4], xbl[4], ybh[4], ybl[4];
    float smx[4], smy[4];
    #pragma unroll
    for (int nt = 0; nt < 4; ++nt) {
        const int row = tm * 64 + nt * 16 + lm;
        const long rb = (gb + row) * PSTRIDE + kg * 8;
        xbh[nt] = *(const bf16x8*)(pxh + rb);
        xbl[nt] = *(const bf16x8*)(pxl + rb);
        ybh[nt] = *(const bf16x8*)(pyh + rb);
        ybl[nt] = *(const bf16x8*)(pyl + rb);
        smx[nt] = sqx[gb + row];
        smy[nt] = sqy[gb + row];
    }

    #pragma unroll
    for (int mt = 0; mt < 4; ++mt) {
        const int arow = tn * 64 + mt * 16 + lm;
        const long ra = (gb + arow) * PSTRIDE + kg * 8;
        const bf16x8 xah = *(const bf16x8*)(pxh + ra);
        const bf16x8 xal = *(const bf16x8*)(pxl + ra);
        const bf16x8 yah = *(const bf16x8*)(pyh + ra);
        const bf16x8 yal = *(const bf16x8*)(pyl + ra);
        float snx[4], sny[4];
        #pragma unroll
        for (int rg = 0; rg < 4; ++rg) {
            const int rr = tn * 64 + mt * 16 + kg * 4 + rg;
            snx[rg] = sqx[gb + rr];
            sny[rg] = sqy[gb + rr];
        }
        #pragma unroll
        for (int nt = 0; nt < 4; ++nt) {
            f32x4 ax = {0.f, 0.f, 0.f, 0.f};
            ax = __builtin_amdgcn_mfma_f32_16x16x32_bf16(xah, xbh[nt], ax, 0, 0, 0);
            ax = __builtin_amdgcn_mfma_f32_16x16x32_bf16(xah, xbl[nt], ax, 0, 0, 0);
            ax = __builtin_amdgcn_mfma_f32_16x16x32_bf16(xal, xbh[nt], ax, 0, 0, 0);
            f32x4 ay = {0.f, 0.f, 0.f, 0.f};
            ay = __builtin_amdgcn_mfma_f32_16x16x32_bf16(yah, ybh[nt], ay, 0, 0, 0);
            ay = __builtin_amdgcn_mfma_f32_16x16x32_bf16(yah, ybl[nt], ay, 0, 0, 0);
            ay = __builtin_amdgcn_mfma_f32_16x16x32_bf16(yal, ybh[nt], ay, 0, 0, 0);
            #pragma unroll
            for (int rg = 0; rg < 4; ++rg) {
                const int row = tn * 64 + mt * 16 + kg * 4 + rg;
                const int col = tm * 64 + nt * 16 + lm;
                const float d2x = fmaxf(fmaf(-2.0f, ax[rg], snx[rg] + smx[nt]), 0.0f);
                const float d2y = fmaxf(fmaf(-2.0f, ay[rg], sny[rg] + smy[nt]), 0.0f);
                const float dx = __builtin_amdgcn_sqrtf(d2x);
                const float dy = __builtin_amdgcn_sqrtf(d2y);
                out[(gb + row) * S + col] = fmaf(wx, dx, wyc * dy);
            }
        }
    }
}

// ---------------------------------------------------------------------------
extern "C" void kernel_launch(void* const* d_in, const int* in_sizes, int n_in,
                              void* d_out, int out_size, void* d_ws, size_t ws_size,
                              hipStream_t stream) {
    const float* q    = (const float*)d_in[0];
    const float* attn = (const float*)d_in[1];
    const float* Ex   = (const float*)d_in[2];
    const float* Ey   = (const float*)d_in[3];
    const float* wxp  = (const float*)d_in[4];
    float* out = (float*)d_out;

    // workspace: pxh|pxl|pyh|pyl (bf16, PSTRIDE) | sqx|sqy  (~14.6 MB)
    __bf16* pxh = (__bf16*)d_ws;
    __bf16* pxl = pxh + (long)NROWS * PSTRIDE;
    __bf16* pyh = pxl + (long)NROWS * PSTRIDE;
    __bf16* pyl = pyh + (long)NROWS * PSTRIDE;
    float* sqx = (float*)(pyl + (long)NROWS * PSTRIDE);
    float* sqy = sqx + NROWS;

    cope2_kernel<<<dim3(36, NH, 8), 256, 0, stream>>>(
        attn, q, Ex, Ey, pxh, pxl, pyh, pyl, sqx, sqy);
    dist_kernel<<<1944, 256, 0, stream>>>(pxh, pxl, pyh, pyl,
                                          sqx, sqy, wxp, out);
}